// Round 8
// baseline (446.004 us; speedup 1.0000x reference)
//
#include <hip/hip_runtime.h>
#include <math.h>

#define B_    2
#define N_    2048
#define DIM_  1024
#define H_    16
#define HD_   64
#define TDIM  3072      // 3*DIM
#define ROWS  4096      // B*N
#define PI_F  3.14159265358979323846f
#define SCALE_F 0.125f

typedef short short8 __attribute__((ext_vector_type(8)));
typedef float f32x4 __attribute__((ext_vector_type(4)));
typedef float f32x16 __attribute__((ext_vector_type(16)));
typedef unsigned u32x4 __attribute__((ext_vector_type(4)));
typedef unsigned short ushort_t;

__device__ __forceinline__ float wave_sum(float v) {
#pragma unroll
  for (int off = 32; off > 0; off >>= 1) v += __shfl_xor(v, off, 64);
  return v;
}

// 2-op bf16 round (round-half-up)
__device__ __forceinline__ unsigned short f2bf(float x) {
  return (unsigned short)((__float_as_uint(x) + 0x8000u) >> 16);
}
__device__ __forceinline__ float bf2f(unsigned short h) {
  return __uint_as_float(((unsigned)h) << 16);
}
// 1/max(sqrt(s),1e-12) via v_rsq
__device__ __forceinline__ float inv_norm(float s) {
  return __builtin_amdgcn_rsqf(fmaxf(s, 1e-24f));
}
__device__ __forceinline__ float fast_tanh(float x) {
  return 1.0f - 2.0f / (__expf(2.0f * x) + 1.0f);
}

// async global->LDS, 16B per lane; LDS dest = wave-uniform base + lane*16
__device__ __forceinline__ void gl_lds16(const void* g, void* l) {
  __builtin_amdgcn_global_load_lds(
      (const __attribute__((address_space(1))) unsigned int*)g,
      (__attribute__((address_space(3))) unsigned int*)l, 16, 0, 0);
}

// ---------------------------------------------------------------------------
__global__ __launch_bounds__(256) void zero_sumsq(float* __restrict__ s) {
  const int i = threadIdx.x;
#pragma unroll
  for (int j = 0; j < 16; ++j) s[j * 256 + i] = 0.0f;
}

// ---------------------------------------------------------------------------
// M = (I + 0.1*Wf)^10 (64x64); emit transposed split-bf16 Ms[2][64][64]
// ---------------------------------------------------------------------------
__global__ __launch_bounds__(256) void compute_M(const float* __restrict__ Wf,
                                                 ushort_t* __restrict__ Ms) {
  __shared__ float A[4096], Mc[4096], Mn[4096];
  const int tid = threadIdx.x;
  for (int i = tid; i < 4096; i += 256) {
    float a = 0.1f * Wf[i] + (((i >> 6) == (i & 63)) ? 1.0f : 0.0f);
    A[i] = a; Mc[i] = a;
  }
  __syncthreads();
  for (int it = 0; it < 9; ++it) {
    for (int i = tid; i < 4096; i += 256) {
      const int r = i >> 6, c = i & 63;
      float s = 0.0f;
      for (int e = 0; e < 64; ++e) s = fmaf(Mc[r * 64 + e], A[e * 64 + c], s);
      Mn[i] = s;
    }
    __syncthreads();
    for (int i = tid; i < 4096; i += 256) Mc[i] = Mn[i];
    __syncthreads();
  }
  for (int i = tid; i < 4096; i += 256) {
    const int n = i >> 6, k = i & 63;
    const float v = Mc[k * 64 + n];
    const ushort_t hi = f2bf(v);
    Ms[i] = hi; Ms[4096 + i] = f2bf(v - bf2f(hi));
  }
}

// ---------------------------------------------------------------------------
__global__ __launch_bounds__(256) void prep_w(const float* __restrict__ Wp1,
                                              const float* __restrict__ Wp2,
                                              ushort_t* __restrict__ W1s,
                                              ushort_t* __restrict__ W2s) {
  const int tid = threadIdx.x;
  for (int i = tid; i < 8192; i += 256) {
    const int n = i >> 6, k = i & 63;
    const float v = Wp1[k * 128 + n];
    const ushort_t hi = f2bf(v);
    W1s[i] = hi; W1s[8192 + i] = f2bf(v - bf2f(hi));
  }
  for (int i = tid; i < 8192; i += 256) {
    const int n = i >> 7, k = i & 127;
    const float v = Wp2[k * 64 + n];
    const ushort_t hi = f2bf(v);
    W2s[i] = hi; W2s[8192 + i] = f2bf(v - bf2f(hi));
  }
}

// ---------------------------------------------------------------------------
__global__ __launch_bounds__(256) void split_X(const float* __restrict__ X,
                                               unsigned short* __restrict__ Xs) {
  const int gid = blockIdx.x * 256 + threadIdx.x;
  const int m = gid >> 8, c = (gid & 255) * 4;
  float4 v = *(const float4*)&X[(size_t)m * 1024 + c];
  ushort4 hi, lo;
  hi.x = f2bf(v.x); lo.x = f2bf(v.x - bf2f(hi.x));
  hi.y = f2bf(v.y); lo.y = f2bf(v.y - bf2f(hi.y));
  hi.z = f2bf(v.z); lo.z = f2bf(v.z - bf2f(hi.z));
  hi.w = f2bf(v.w); lo.w = f2bf(v.w - bf2f(hi.w));
  *(ushort4*)&Xs[(size_t)m * 2048 + c] = hi;
  *(ushort4*)&Xs[(size_t)m * 2048 + 1024 + c] = lo;
}

__global__ __launch_bounds__(256) void split_W(const float* __restrict__ W,
                                               unsigned short* __restrict__ Wt) {
  __shared__ float T[64][68];
  const int n0 = blockIdx.x * 64, k0 = blockIdx.y * 64;
  const int tid = threadIdx.x;
  for (int l = tid; l < 1024; l += 256) {
    const int r = l >> 4, c = (l & 15) * 4;
    *(float4*)&T[r][c] = *(const float4*)&W[(size_t)(k0 + r) * TDIM + n0 + c];
  }
  __syncthreads();
  const int n = tid >> 2, q = (tid & 3) * 16;
  alignas(16) unsigned short hi16[16];
  alignas(16) unsigned short lo16[16];
#pragma unroll
  for (int j = 0; j < 16; ++j) {
    const float v = T[q + j][n];
    const unsigned short h = f2bf(v);
    hi16[j] = h; lo16[j] = f2bf(v - bf2f(h));
  }
  unsigned short* dst = &Wt[(size_t)(n0 + n) * 2048];
  *(uint4*)&dst[k0 + q]          = *(uint4*)&hi16[0];
  *(uint4*)&dst[k0 + q + 8]      = *(uint4*)&hi16[8];
  *(uint4*)&dst[1024 + k0 + q]     = *(uint4*)&lo16[0];
  *(uint4*)&dst[1024 + k0 + q + 8] = *(uint4*)&lo16[8];
}

// ---------------------------------------------------------------------------
// gemm5: two-phase split-bf16 MFMA (unchanged from R7)
// ---------------------------------------------------------------------------
__global__ __launch_bounds__(256) void gemm5(const unsigned short* __restrict__ Xs,
                                             const unsigned short* __restrict__ Wt,
                                             const float* __restrict__ bias,
                                             float* __restrict__ C,
                                             float* __restrict__ sumsq) {
  __shared__ ushort_t As[128 * 64];
  __shared__ ushort_t B0[128 * 64];
  __shared__ ushort_t B1[128 * 64];
  const int tid = threadIdx.x;
  const int wv = tid >> 6, ln = tid & 63;
  const int l16 = ln & 15, quad = ln >> 4;
  const int wrow = wv >> 1, wcol = wv & 1;
  const int row0 = blockIdx.y * 128, col0 = blockIdx.x * 128;
  const int srow = ln >> 3;
  const int sgrp = (ln & 7) ^ srow;
  f32x4 acc[4][4];
#pragma unroll
  for (int i = 0; i < 4; ++i)
#pragma unroll
    for (int j = 0; j < 4; ++j) acc[i][j] = {0.f, 0.f, 0.f, 0.f};

  for (int k0 = 0; k0 < 1024; k0 += 64) {
    __syncthreads();
#pragma unroll
    for (int i = 0; i < 4; ++i) {
      const int ci = wv * 4 + i;
      const int r = ci * 8 + srow;
      gl_lds16(&Xs[(size_t)(row0 + r) * 2048 + k0 + sgrp * 8],
               (char*)As + ci * 1024);
      gl_lds16(&Wt[(size_t)(col0 + r) * 2048 + k0 + sgrp * 8],
               (char*)B0 + ci * 1024);
      gl_lds16(&Wt[(size_t)(col0 + r) * 2048 + 1024 + k0 + sgrp * 8],
               (char*)B1 + ci * 1024);
    }
    __syncthreads();
#pragma unroll
    for (int kk = 0; kk < 2; ++kk) {
      const int slot = (kk * 4 + quad) ^ (l16 & 7);
      short8 af[4], b[4];
#pragma unroll
      for (int mi = 0; mi < 4; ++mi)
        af[mi] = *(const short8*)&As[(wrow * 64 + mi * 16 + l16) * 64 + slot * 8];
#pragma unroll
      for (int ni = 0; ni < 4; ++ni)
        b[ni] = *(const short8*)&B0[(wcol * 64 + ni * 16 + l16) * 64 + slot * 8];
#pragma unroll
      for (int mi = 0; mi < 4; ++mi)
#pragma unroll
        for (int ni = 0; ni < 4; ++ni)
          acc[mi][ni] = __builtin_amdgcn_mfma_f32_16x16x32_bf16(af[mi], b[ni], acc[mi][ni], 0, 0, 0);
#pragma unroll
      for (int ni = 0; ni < 4; ++ni)
        b[ni] = *(const short8*)&B1[(wcol * 64 + ni * 16 + l16) * 64 + slot * 8];
#pragma unroll
      for (int mi = 0; mi < 4; ++mi)
#pragma unroll
        for (int ni = 0; ni < 4; ++ni)
          acc[mi][ni] = __builtin_amdgcn_mfma_f32_16x16x32_bf16(af[mi], b[ni], acc[mi][ni], 0, 0, 0);
    }
  }
  for (int k0 = 0; k0 < 1024; k0 += 64) {
    __syncthreads();
#pragma unroll
    for (int i = 0; i < 4; ++i) {
      const int ci = wv * 4 + i;
      const int r = ci * 8 + srow;
      gl_lds16(&Xs[(size_t)(row0 + r) * 2048 + 1024 + k0 + sgrp * 8],
               (char*)As + ci * 1024);
      gl_lds16(&Wt[(size_t)(col0 + r) * 2048 + k0 + sgrp * 8],
               (char*)B0 + ci * 1024);
    }
    __syncthreads();
#pragma unroll
    for (int kk = 0; kk < 2; ++kk) {
      const int slot = (kk * 4 + quad) ^ (l16 & 7);
      short8 af[4], b[4];
#pragma unroll
      for (int mi = 0; mi < 4; ++mi)
        af[mi] = *(const short8*)&As[(wrow * 64 + mi * 16 + l16) * 64 + slot * 8];
#pragma unroll
      for (int ni = 0; ni < 4; ++ni)
        b[ni] = *(const short8*)&B0[(wcol * 64 + ni * 16 + l16) * 64 + slot * 8];
#pragma unroll
      for (int mi = 0; mi < 4; ++mi)
#pragma unroll
        for (int ni = 0; ni < 4; ++ni)
          acc[mi][ni] = __builtin_amdgcn_mfma_f32_16x16x32_bf16(af[mi], b[ni], acc[mi][ni], 0, 0, 0);
    }
  }
  float ps[4][4];
#pragma unroll
  for (int mi = 0; mi < 4; ++mi)
#pragma unroll
    for (int r = 0; r < 4; ++r) ps[mi][r] = 0.f;
#pragma unroll
  for (int ni = 0; ni < 4; ++ni) {
    const int col = col0 + wcol * 64 + ni * 16 + l16;
    const float bb = bias[col];
#pragma unroll
    for (int mi = 0; mi < 4; ++mi) {
#pragma unroll
      for (int r = 0; r < 4; ++r) {
        const int row = row0 + wrow * 64 + mi * 16 + quad * 4 + r;
        const float o = acc[mi][ni][r] + bb;
        C[(size_t)row * TDIM + col] = o;
        ps[mi][r] = fmaf(o, o, ps[mi][r]);
      }
    }
  }
#pragma unroll
  for (int mi = 0; mi < 4; ++mi) {
#pragma unroll
    for (int r = 0; r < 4; ++r) {
      float v = ps[mi][r];
      v += __shfl_xor(v, 1, 64);
      v += __shfl_xor(v, 2, 64);
      v += __shfl_xor(v, 4, 64);
      v += __shfl_xor(v, 8, 64);
      if (l16 == 0)
        atomicAdd(&sumsq[row0 + wrow * 64 + mi * 16 + quad * 4 + r], v);
    }
  }
}

// ---------------------------------------------------------------------------
// prep v2: latency-oriented rework.
// - weight frags batched into registers per stage (one L2 round-trip/stage)
// - H stored bf16-only (error -> absmax ~7e-4, see journal) =>
//   LDS 45.5 -> 35.6 KB => 4 blocks/CU; L2 terms 3->2
// - Vt transpose in-register (8 shfls) -> one dwordx2 store per lane
// ---------------------------------------------------------------------------
__global__ __launch_bounds__(256, 4) void prep_mfma(
    const float* __restrict__ qkv, const float* __restrict__ sumsq,
    const ushort_t* __restrict__ W1s, const float* __restrict__ bp1,
    const ushort_t* __restrict__ W2s, const float* __restrict__ bp2,
    const ushort_t* __restrict__ Ms,
    ushort_t* __restrict__ Qc, ushort_t* __restrict__ Kc,
    ushort_t* __restrict__ Vt) {
  __shared__ __align__(16) char smem[36480];
  ushort_t (*Th)[72]  = (ushort_t(*)[72])(smem + 0);       // 4608
  ushort_t (*Tl)[72]  = (ushort_t(*)[72])(smem + 4608);    // 4608
  ushort_t (*Hh)[136] = (ushort_t(*)[136])(smem + 9216);   // 8704 (bf16-only)
  ushort_t (*Zrh)[72] = (ushort_t(*)[72])(smem + 17920);
  ushort_t (*Zrl)[72] = (ushort_t(*)[72])(smem + 22528);
  ushort_t (*Zih)[72] = (ushort_t(*)[72])(smem + 27136);
  ushort_t (*Zil)[72] = (ushort_t(*)[72])(smem + 31744);   // -> 36352
  float (*Fr)[68] = (float(*)[68])(smem + 0);              // alias T (dead)
  float (*Fi)[68] = (float(*)[68])(smem + 9216);           // alias Hh (dead)
  float* invt = (float*)(smem + 36352);                    // [32]

  const int tid = threadIdx.x;
  const int wv = tid >> 6, ln = tid & 63;
  const int l16 = ln & 15, quad = ln >> 4;
  const int g0 = blockIdx.x * 16;
  const int bh = g0 >> 11, n0 = g0 & 2047;
  const int b = bh >> 4, h = bh & 15;

  // ---- stage A: load, norms, V out (shfl transpose), T split into LDS
  {
    const int row = tid >> 4;          // 0..15 (wave wv covers rows wv*4..+3)
    const int c4 = (tid & 15) * 4;
    const int n = n0 + row;
    const size_t base = ((size_t)(b * N_ + n)) * TDIM + h * HD_;
    const float inv = inv_norm(sumsq[b * N_ + n]);
    float4 q4 = *(const float4*)&qkv[base + c4];
    float4 k4 = *(const float4*)&qkv[base + 1024 + c4];
    float4 v4 = *(const float4*)&qkv[base + 2048 + c4];
    q4.x *= inv; q4.y *= inv; q4.z *= inv; q4.w *= inv;
    k4.x *= inv; k4.y *= inv; k4.z *= inv; k4.w *= inv;
    v4.x *= inv; v4.y *= inv; v4.z *= inv; v4.w *= inv;
    float sq = q4.x * q4.x + q4.y * q4.y + q4.z * q4.z + q4.w * q4.w;
    float sk = k4.x * k4.x + k4.y * k4.y + k4.z * k4.z + k4.w * k4.w;
    float sv = v4.x * v4.x + v4.y * v4.y + v4.z * v4.z + v4.w * v4.w;
#pragma unroll
    for (int off = 1; off < 16; off <<= 1) {
      sq += __shfl_xor(sq, off, 64);
      sk += __shfl_xor(sk, off, 64);
      sv += __shfl_xor(sv, off, 64);
    }
    if ((tid & 15) == 0) {
      invt[row]      = inv_norm(sq);
      invt[16 + row] = inv_norm(sk);
    }
    const float vinv = inv_norm(sv);
    // pack this thread's 4 |v| bf16 values, then in-register transpose:
    // target lane d(=ln) holds positions wv*4..wv*4+3 for dim d.
    const unsigned u0 = (unsigned)f2bf(fabsf(v4.x) * vinv) |
                        ((unsigned)f2bf(fabsf(v4.y) * vinv) << 16);
    const unsigned u1 = (unsigned)f2bf(fabsf(v4.z) * vinv) |
                        ((unsigned)f2bf(fabsf(v4.w) * vinv) << 16);
    unsigned o16[4];
#pragma unroll
    for (int p = 0; p < 4; ++p) {
      const int src = p * 16 + (ln >> 2);
      const unsigned s0 = (unsigned)__shfl((int)u0, src, 64);
      const unsigned s1 = (unsigned)__shfl((int)u1, src, 64);
      const unsigned sel = (ln & 2) ? s1 : s0;
      o16[p] = (ln & 1) ? (sel >> 16) : (sel & 0xffffu);
    }
    uint2 st;
    st.x = o16[0] | (o16[1] << 16);
    st.y = o16[2] | (o16[3] << 16);
    *(uint2*)&Vt[((size_t)(bh * 64) + ln) * N_ + n0 + wv * 4] = st;

    ushort4 qh, ql, kh, kl;
    qh.x = f2bf(q4.x); ql.x = f2bf(q4.x - bf2f(qh.x));
    qh.y = f2bf(q4.y); ql.y = f2bf(q4.y - bf2f(qh.y));
    qh.z = f2bf(q4.z); ql.z = f2bf(q4.z - bf2f(qh.z));
    qh.w = f2bf(q4.w); ql.w = f2bf(q4.w - bf2f(qh.w));
    kh.x = f2bf(k4.x); kl.x = f2bf(k4.x - bf2f(kh.x));
    kh.y = f2bf(k4.y); kl.y = f2bf(k4.y - bf2f(kh.y));
    kh.z = f2bf(k4.z); kl.z = f2bf(k4.z - bf2f(kh.z));
    kh.w = f2bf(k4.w); kl.w = f2bf(k4.w - bf2f(kh.w));
    *(ushort4*)&Th[row][c4] = qh;      *(ushort4*)&Tl[row][c4] = ql;
    *(ushort4*)&Th[16 + row][c4] = kh; *(ushort4*)&Tl[16 + row][c4] = kl;
  }
  __syncthreads();

  const int rt = wv & 1;
  const int ch = wv >> 1;

  // ---- layer 1: H = tanh(T @ Wp1 + b1)  (weights batched to regs first)
  {
    short8 w1h[4][2], w1l[4][2];
#pragma unroll
    for (int ct = 0; ct < 4; ++ct)
#pragma unroll
      for (int s = 0; s < 2; ++s) {
        const int colg = ch * 64 + ct * 16 + l16;
        w1h[ct][s] = *(const short8*)&W1s[(size_t)colg * 64 + s * 32 + quad * 8];
        w1l[ct][s] = *(const short8*)&W1s[8192 + (size_t)colg * 64 + s * 32 + quad * 8];
      }
    short8 aT[2][2];
#pragma unroll
    for (int s = 0; s < 2; ++s) {
      aT[s][0] = *(const short8*)&Th[rt * 16 + l16][s * 32 + quad * 8];
      aT[s][1] = *(const short8*)&Tl[rt * 16 + l16][s * 32 + quad * 8];
    }
#pragma unroll
    for (int ct = 0; ct < 4; ++ct) {
      const int colg = ch * 64 + ct * 16 + l16;
      f32x4 c = {0.f, 0.f, 0.f, 0.f};
#pragma unroll
      for (int s = 0; s < 2; ++s) {
        c = __builtin_amdgcn_mfma_f32_16x16x32_bf16(aT[s][0], w1h[ct][s], c, 0, 0, 0);
        c = __builtin_amdgcn_mfma_f32_16x16x32_bf16(aT[s][0], w1l[ct][s], c, 0, 0, 0);
        c = __builtin_amdgcn_mfma_f32_16x16x32_bf16(aT[s][1], w1h[ct][s], c, 0, 0, 0);
      }
      const float bb = bp1[colg];
#pragma unroll
      for (int r = 0; r < 4; ++r)
        Hh[rt * 16 + quad * 4 + r][colg] = f2bf(fast_tanh(c[r] + bb));
    }
  }
  __syncthreads();

  // ---- layer 2 + z  (H bf16-only: 2 terms)
  {
    short8 w2h[2][4], w2l[2][4];
#pragma unroll
    for (int t2 = 0; t2 < 2; ++t2)
#pragma unroll
      for (int s = 0; s < 4; ++s) {
        const int d = (ch * 2 + t2) * 16 + l16;
        w2h[t2][s] = *(const short8*)&W2s[(size_t)d * 128 + s * 32 + quad * 8];
        w2l[t2][s] = *(const short8*)&W2s[8192 + (size_t)d * 128 + s * 32 + quad * 8];
      }
    short8 aH[4];
#pragma unroll
    for (int s = 0; s < 4; ++s)
      aH[s] = *(const short8*)&Hh[rt * 16 + l16][s * 32 + quad * 8];
#pragma unroll
    for (int t2 = 0; t2 < 2; ++t2) {
      const int d = (ch * 2 + t2) * 16 + l16;
      f32x4 c = {0.f, 0.f, 0.f, 0.f};
#pragma unroll
      for (int s = 0; s < 4; ++s) {
        c = __builtin_amdgcn_mfma_f32_16x16x32_bf16(aH[s], w2h[t2][s], c, 0, 0, 0);
        c = __builtin_amdgcn_mfma_f32_16x16x32_bf16(aH[s], w2l[t2][s], c, 0, 0, 0);
      }
      const float b2v = bp2[d];
#pragma unroll
      for (int r = 0; r < 4; ++r) {
        const int row = rt * 16 + quad * 4 + r;
        const float ph = fast_tanh(c[r] + b2v) * PI_F;
        const float tv = bf2f(Th[row][d]) + bf2f(Tl[row][d]);
        const float amp = tv * invt[row];
        float sp, cp;
        __sincosf(ph, &sp, &cp);
        const float zr = amp * cp;
        const float zi = amp * sp;
        const ushort_t zrh = f2bf(zr);
        const ushort_t zih = f2bf(zi);
        Zrh[row][d] = zrh; Zrl[row][d] = f2bf(zr - bf2f(zrh));
        Zih[row][d] = zih; Zil[row][d] = f2bf(zi - bf2f(zih));
      }
    }
  }
  __syncthreads();

  // ---- flow: F = Z @ M (per-wave component ch); F aliases dead T/H
  {
    short8 msh[4][2], msl[4][2];
#pragma unroll
    for (int ct = 0; ct < 4; ++ct)
#pragma unroll
      for (int s = 0; s < 2; ++s) {
        const int colg = ct * 16 + l16;
        msh[ct][s] = *(const short8*)&Ms[(size_t)colg * 64 + s * 32 + quad * 8];
        msl[ct][s] = *(const short8*)&Ms[4096 + (size_t)colg * 64 + s * 32 + quad * 8];
      }
    const ushort_t (*Zh)[72] = ch ? Zih : Zrh;
    const ushort_t (*Zl)[72] = ch ? Zil : Zrl;
    float (*Fo)[68] = ch ? Fi : Fr;
    short8 aZ[2][2];
#pragma unroll
    for (int s = 0; s < 2; ++s) {
      aZ[s][0] = *(const short8*)&Zh[rt * 16 + l16][s * 32 + quad * 8];
      aZ[s][1] = *(const short8*)&Zl[rt * 16 + l16][s * 32 + quad * 8];
    }
    f32x4 cc[4];
#pragma unroll
    for (int ct = 0; ct < 4; ++ct) {
      f32x4 c = {0.f, 0.f, 0.f, 0.f};
#pragma unroll
      for (int s = 0; s < 2; ++s) {
        c = __builtin_amdgcn_mfma_f32_16x16x32_bf16(aZ[s][0], msh[ct][s], c, 0, 0, 0);
        c = __builtin_amdgcn_mfma_f32_16x16x32_bf16(aZ[s][0], msl[ct][s], c, 0, 0, 0);
        c = __builtin_amdgcn_mfma_f32_16x16x32_bf16(aZ[s][1], msh[ct][s], c, 0, 0, 0);
      }
      cc[ct] = c;
    }
    __syncthreads();   // all waves done reading Z before F overwrites T/H
#pragma unroll
    for (int ct = 0; ct < 4; ++ct)
#pragma unroll
      for (int r = 0; r < 4; ++r)
        Fo[rt * 16 + quad * 4 + r][ct * 16 + l16] = cc[ct][r];
  }
  __syncthreads();

  // ---- normalize + parallel transport + outputs
#pragma unroll
  for (int jj = 0; jj < 4; ++jj) {
    const int j = wv * 4 + jj;
    const int n = n0 + j;
    float qr = Fr[j][ln], qi = Fi[j][ln];
    float kr = Fr[16 + j][ln], ki = Fi[16 + j][ln];
    {
      const float inv = inv_norm(wave_sum(fmaf(qr, qr, qi * qi)));
      qr *= inv; qi *= inv;
    }
    {
      const float inv = inv_norm(wave_sum(fmaf(kr, kr, ki * ki)));
      kr *= inv; ki *= inv;
    }
    const size_t o = ((size_t)bh * N_ + n) * 128;
    Qc[o + ln]      = f2bf(qr);
    Qc[o + 64 + ln] = f2bf(qi);
    const float dr = kr - qr, di = ki - qi;
    const float sr = wave_sum(fmaf(dr, dr, -di * di));
    const float si = wave_sum(2.0f * dr * di);
    const float rad = sqrtf(fmaf(sr, sr, si * si));
    const float ur = sqrtf(fmaxf((rad + sr) * 0.5f, 0.0f));
    const float ui = copysignf(sqrtf(fmaxf((rad - sr) * 0.5f, 0.0f)), si);
    const float er = __expf(10.0f * ur);
    float s10, c10;
    __sincosf(10.0f * ui, &s10, &c10);
    const float exr = er * c10;
    const float exi = er * s10;
    const float dnr = 1.0f + exr, dni = exi;
    const float rd2 = __builtin_amdgcn_rcpf(fmaf(dnr, dnr, dni * dni));
    const float tfr = dnr * rd2, tfi = -dni * rd2;
    const float omr = 1.0f - tfr, omi = -tfi;
    const float ktr = kr * tfr - ki * tfi + qr * omr - qi * omi;
    const float kti = kr * tfi + ki * tfr + qr * omi + qi * omr;
    const float inv2 = inv_norm(wave_sum(fmaf(ktr, ktr, kti * kti)));
    Kc[o + ln]      = f2bf(ktr * inv2);
    Kc[o + 64 + ln] = f2bf(-kti * inv2);   // negated: S = qr.kr + qi.(-ki)
  }
}

// ---------------------------------------------------------------------------
// attn3: 32x32x16 MFMA flash -- unchanged
// ---------------------------------------------------------------------------
__global__ __launch_bounds__(256, 2) void attn3(
    const ushort_t* __restrict__ Qc, const ushort_t* __restrict__ Kc,
    const ushort_t* __restrict__ Vt, float* __restrict__ out) {
  __shared__ __align__(16) char smem[35328];
  ushort_t* Ks = (ushort_t*)smem;
  ushort_t* Vs = (ushort_t*)(smem + 16384);
  float (*Of)[68] = (float(*)[68])smem;
  float* Dd = (float*)(smem + 34816);

  const int tid = threadIdx.x;
  const int wv = tid >> 6, ln = tid & 63;
  const int l31 = ln & 31, hi = ln >> 5;
  const int qh = wv & 1, kh = wv >> 1;
  const int bh = blockIdx.y;
  const int q0 = blockIdx.x * 128;
  const size_t hb = (size_t)bh * N_;

  short8 qf[2][8];
#pragma unroll
  for (int nt = 0; nt < 2; ++nt) {
    const size_t qrow = (hb + q0 + qh * 64 + nt * 32 + l31) * 128;
#pragma unroll
    for (int s = 0; s < 8; ++s)
      qf[nt][s] = *(const short8*)&Qc[qrow + s * 16 + hi * 8];
  }

  f32x16 oacc[2][2];
#pragma unroll
  for (int i = 0; i < 2; ++i)
#pragma unroll
    for (int j = 0; j < 2; ++j)
#pragma unroll
      for (int r = 0; r < 16; ++r) oacc[i][j][r] = 0.f;
  float den[2] = {0.f, 0.f};

  const int rK = kh * 32 + l31;
  for (int kt = 0; kt < N_ / 64; ++kt) {
    const size_t kbase = (hb + kt * 64) * 128;
    __syncthreads();
#pragma unroll
    for (int i = 0; i < 4; ++i) {
      const int l = tid + i * 256;
      const int r = l >> 4, c = l & 15;
      uint4 v = *(const uint4*)&Kc[kbase + (size_t)r * 128 + c * 8];
      *(uint4*)&Ks[r * 128 + ((c ^ (r & 15)) * 8)] = v;
    }
#pragma unroll
    for (int i = 0; i < 2; ++i) {
      const int l = tid + i * 256;
      const int r = l >> 3, c = l & 7;
      uint4 v = *(const uint4*)&Vt[((size_t)bh * 64 + r) * N_ + kt * 64 + c * 8];
      *(uint4*)&Vs[r * 128 + ((c ^ (r & 15)) * 8)] = v;
    }
    __syncthreads();

    f32x16 sacc[2];
#pragma unroll
    for (int nt = 0; nt < 2; ++nt)
#pragma unroll
      for (int r = 0; r < 16; ++r) sacc[nt][r] = 0.f;
#pragma unroll
    for (int s = 0; s < 8; ++s) {
      const int c = s * 2 + hi;
      short8 ak = *(const short8*)&Ks[rK * 128 + ((c ^ (rK & 15)) * 8)];
      sacc[0] = __builtin_amdgcn_mfma_f32_32x32x16_bf16(ak, qf[0][s], sacc[0], 0, 0, 0);
      sacc[1] = __builtin_amdgcn_mfma_f32_32x32x16_bf16(ak, qf[1][s], sacc[1], 0, 0, 0);
    }

    short8 pfrag[2][2];
#pragma unroll
    for (int nt = 0; nt < 2; ++nt) {
      float pv[16];
      float dl = 0.f;
#pragma unroll
      for (int r = 0; r < 16; ++r) {
        pv[r] = __expf(sacc[nt][r] * SCALE_F);
        dl += pv[r];
      }
      den[nt] += dl;
      unsigned u8a[8], pu[8];
#pragma unroll
      for (int t = 0; t < 8; ++t)
        u8a[t] = (unsigned)f2bf(pv[2 * t]) | ((unsigned)f2bf(pv[2 * t + 1]) << 16);
#pragma unroll
      for (int t = 0; t < 8; ++t)
        pu[t] = (unsigned)__shfl_xor((int)u8a[t], 32, 64);
#pragma unroll
      for (int s2 = 0; s2 < 2; ++s2) {
        u32x4 fu;
        if (hi == 0) {
          fu[0] = u8a[4 * s2]; fu[1] = u8a[4 * s2 + 1];
          fu[2] = pu[4 * s2];  fu[3] = pu[4 * s2 + 1];
        } else {
          fu[0] = pu[4 * s2 + 2];  fu[1] = pu[4 * s2 + 3];
          fu[2] = u8a[4 * s2 + 2]; fu[3] = u8a[4 * s2 + 3];
        }
        pfrag[nt][s2] = __builtin_bit_cast(short8, fu);
      }
    }

#pragma unroll
    for (int s2 = 0; s2 < 2; ++s2) {
#pragma unroll
      for (int dt = 0; dt < 2; ++dt) {
        const int rV = dt * 32 + l31;
        const int c = kh * 4 + s2 * 2 + hi;
        short8 bv = *(const short8*)&Vs[rV * 128 + ((c ^ (rV & 15)) * 8)];
        oacc[0][dt] = __builtin_amdgcn_mfma_f32_32x32x16_bf16(pfrag[0][s2], bv, oacc[0][dt], 0, 0, 0);
        oacc[1][dt] = __builtin_amdgcn_mfma_f32_32x32x16_bf16(pfrag[1][s2], bv, oacc[1][dt], 0, 0, 0);
      }
    }
  }

#pragma unroll
  for (int nt = 0; nt < 2; ++nt)
    den[nt] += __shfl_xor(den[nt], 32, 64);

  __syncthreads();
  if (kh == 0) {
#pragma unroll
    for (int nt = 0; nt < 2; ++nt) {
#pragma unroll
      for (int dt = 0; dt < 2; ++dt)
#pragma unroll
        for (int r = 0; r < 16; ++r) {
          const int row = qh * 64 + nt * 32 + (r & 3) + 8 * (r >> 2) + 4 * hi;
          Of[row][dt * 32 + l31] = oacc[nt][dt][r];
        }
      if (hi == 0) Dd[qh * 64 + nt * 32 + l31] = den[nt];
    }
  }
  __syncthreads();
  if (kh == 1) {
#pragma unroll
    for (int nt = 0; nt < 2; ++nt) {
#pragma unroll
      for (int dt = 0; dt < 2; ++dt)
#pragma unroll
        for (int r = 0; r < 16; ++r) {
          const int row = qh * 64 + nt * 32 + (r & 3) + 8 * (r >> 2) + 4 * hi;
          Of[row][dt * 32 + l31] += oacc[nt][dt][r];
        }
      if (hi == 0) Dd[qh * 64 + nt * 32 + l31] += den[nt];
    }
  }
  __syncthreads();

  {
    const int ql = tid >> 1, half = tid & 1;
    const int b = bh >> 4, h = bh & 15;
    const float invd = __builtin_amdgcn_rcpf(Dd[ql]);
    float* op = &out[(((size_t)b * N_ + q0 + ql) * H_ + h) * HD_ + half * 32];
#pragma unroll
    for (int j = 0; j < 8; ++j) {
      float4 o = *(const float4*)&Of[ql][half * 32 + j * 4];
      o.x *= invd; o.y *= invd; o.z *= invd; o.w *= invd;
      *(float4*)&op[j * 4] = o;
    }
  }
}

// ---------------------------------------------------------------------------
extern "C" void kernel_launch(void* const* d_in, const int* in_sizes, int n_in,
                              void* d_out, int out_size, void* d_ws, size_t ws_size,
                              hipStream_t stream) {
  const float* x    = (const float*)d_in[0];
  const float* Wqkv = (const float*)d_in[1];
  const float* bqkv = (const float*)d_in[2];
  const float* Wp1  = (const float*)d_in[3];
  const float* bp1  = (const float*)d_in[4];
  const float* Wp2  = (const float*)d_in[5];
  const float* bp2  = (const float*)d_in[6];
  const float* Wf   = (const float*)d_in[7];
  float* out = (float*)d_out;

  char* w = (char*)d_ws;
  float* qkv = (float*)w;               w += (size_t)ROWS * TDIM * 4;
  float* sumsq = (float*)w;             w += (size_t)ROWS * 4;
  ushort_t* Ms  = (ushort_t*)w;         w += 2 * 4096 * 2;
  ushort_t* W1s = (ushort_t*)w;         w += 2 * 8192 * 2;
  ushort_t* W2s = (ushort_t*)w;         w += 2 * 8192 * 2;
  unsigned short* Xs = (unsigned short*)w; w += (size_t)ROWS * 2048 * 2;
  unsigned short* Wt = (unsigned short*)w; w += (size_t)TDIM * 2048 * 2;
  unsigned short* Qc = (unsigned short*)w; w += (size_t)32 * N_ * 128 * 2;
  unsigned short* Kc = (unsigned short*)w; w += (size_t)32 * N_ * 128 * 2;
  unsigned short* Vt = (unsigned short*)w; w += (size_t)32 * 64 * N_ * 2;

  hipLaunchKernelGGL(split_X, dim3(ROWS * 1024 / 4 / 256), dim3(256), 0, stream, x, Xs);
  hipLaunchKernelGGL(split_W, dim3(48, 16), dim3(256), 0, stream, Wqkv, Wt);
  hipLaunchKernelGGL(compute_M, dim3(1), dim3(256), 0, stream, Wf, Ms);
  hipLaunchKernelGGL(prep_w, dim3(1), dim3(256), 0, stream, Wp1, Wp2, W1s, W2s);
  hipLaunchKernelGGL(zero_sumsq, dim3(1), dim3(256), 0, stream, sumsq);
  hipLaunchKernelGGL(gemm5, dim3(24, 32), dim3(256), 0, stream, Xs, Wt, bqkv, qkv, sumsq);
  hipLaunchKernelGGL(prep_mfma, dim3(4096), dim3(256), 0, stream,
                     qkv, sumsq, W1s, bp1, W2s, bp2, Ms, Qc, Kc, Vt);
  hipLaunchKernelGGL(attn3, dim3(N_ / 128, B_ * H_), dim3(256), 0, stream,
                     Qc, Kc, Vt, out);
}

// Round 9
// 422.085 us; speedup vs baseline: 1.0567x; 1.0567x over previous
//
#include <hip/hip_runtime.h>
#include <math.h>

#define B_    2
#define N_    2048
#define DIM_  1024
#define H_    16
#define HD_   64
#define TDIM  3072      // 3*DIM
#define ROWS  4096      // B*N
#define PI_F  3.14159265358979323846f
#define SCALE_F 0.125f

typedef short short8 __attribute__((ext_vector_type(8)));
typedef float f32x4 __attribute__((ext_vector_type(4)));
typedef float f32x16 __attribute__((ext_vector_type(16)));
typedef unsigned u32x4 __attribute__((ext_vector_type(4)));
typedef unsigned short ushort_t;

__device__ __forceinline__ float wave_sum(float v) {
#pragma unroll
  for (int off = 32; off > 0; off >>= 1) v += __shfl_xor(v, off, 64);
  return v;
}

// 2-op bf16 round (round-half-up)
__device__ __forceinline__ unsigned short f2bf(float x) {
  return (unsigned short)((__float_as_uint(x) + 0x8000u) >> 16);
}
__device__ __forceinline__ float bf2f(unsigned short h) {
  return __uint_as_float(((unsigned)h) << 16);
}
__device__ __forceinline__ float inv_norm(float s) {
  return __builtin_amdgcn_rsqf(fmaxf(s, 1e-24f));
}
__device__ __forceinline__ float fast_tanh(float x) {
  return 1.0f - 2.0f / (__expf(2.0f * x) + 1.0f);
}

// async global->LDS, 16B per lane; LDS dest = wave-uniform base + lane*16
__device__ __forceinline__ void gl_lds16(const void* g, void* l) {
  __builtin_amdgcn_global_load_lds(
      (const __attribute__((address_space(1))) unsigned int*)g,
      (__attribute__((address_space(3))) unsigned int*)l, 16, 0, 0);
}

// ---------------------------------------------------------------------------
__global__ __launch_bounds__(256) void zero_sumsq(float* __restrict__ s) {
  const int i = threadIdx.x;
#pragma unroll
  for (int j = 0; j < 16; ++j) s[j * 256 + i] = 0.0f;
}

// ---------------------------------------------------------------------------
// M = (I + 0.1*Wf)^10 (64x64); emit transposed split-bf16 Ms[2][64][64]
// ---------------------------------------------------------------------------
__global__ __launch_bounds__(256) void compute_M(const float* __restrict__ Wf,
                                                 ushort_t* __restrict__ Ms) {
  __shared__ float A[4096], Mc[4096], Mn[4096];
  const int tid = threadIdx.x;
  for (int i = tid; i < 4096; i += 256) {
    float a = 0.1f * Wf[i] + (((i >> 6) == (i & 63)) ? 1.0f : 0.0f);
    A[i] = a; Mc[i] = a;
  }
  __syncthreads();
  for (int it = 0; it < 9; ++it) {
    for (int i = tid; i < 4096; i += 256) {
      const int r = i >> 6, c = i & 63;
      float s = 0.0f;
      for (int e = 0; e < 64; ++e) s = fmaf(Mc[r * 64 + e], A[e * 64 + c], s);
      Mn[i] = s;
    }
    __syncthreads();
    for (int i = tid; i < 4096; i += 256) Mc[i] = Mn[i];
    __syncthreads();
  }
  for (int i = tid; i < 4096; i += 256) {
    const int n = i >> 6, k = i & 63;
    const float v = Mc[k * 64 + n];
    const ushort_t hi = f2bf(v);
    Ms[i] = hi; Ms[4096 + i] = f2bf(v - bf2f(hi));
  }
}

// ---------------------------------------------------------------------------
__global__ __launch_bounds__(256) void prep_w(const float* __restrict__ Wp1,
                                              const float* __restrict__ Wp2,
                                              ushort_t* __restrict__ W1s,
                                              ushort_t* __restrict__ W2s) {
  const int tid = threadIdx.x;
  for (int i = tid; i < 8192; i += 256) {
    const int n = i >> 6, k = i & 63;
    const float v = Wp1[k * 128 + n];
    const ushort_t hi = f2bf(v);
    W1s[i] = hi; W1s[8192 + i] = f2bf(v - bf2f(hi));
  }
  for (int i = tid; i < 8192; i += 256) {
    const int n = i >> 7, k = i & 127;
    const float v = Wp2[k * 64 + n];
    const ushort_t hi = f2bf(v);
    W2s[i] = hi; W2s[8192 + i] = f2bf(v - bf2f(hi));
  }
}

// ---------------------------------------------------------------------------
__global__ __launch_bounds__(256) void split_X(const float* __restrict__ X,
                                               unsigned short* __restrict__ Xs) {
  const int gid = blockIdx.x * 256 + threadIdx.x;
  const int m = gid >> 8, c = (gid & 255) * 4;
  float4 v = *(const float4*)&X[(size_t)m * 1024 + c];
  ushort4 hi, lo;
  hi.x = f2bf(v.x); lo.x = f2bf(v.x - bf2f(hi.x));
  hi.y = f2bf(v.y); lo.y = f2bf(v.y - bf2f(hi.y));
  hi.z = f2bf(v.z); lo.z = f2bf(v.z - bf2f(hi.z));
  hi.w = f2bf(v.w); lo.w = f2bf(v.w - bf2f(hi.w));
  *(ushort4*)&Xs[(size_t)m * 2048 + c] = hi;
  *(ushort4*)&Xs[(size_t)m * 2048 + 1024 + c] = lo;
}

__global__ __launch_bounds__(256) void split_W(const float* __restrict__ W,
                                               unsigned short* __restrict__ Wt) {
  __shared__ float T[64][68];
  const int n0 = blockIdx.x * 64, k0 = blockIdx.y * 64;
  const int tid = threadIdx.x;
  for (int l = tid; l < 1024; l += 256) {
    const int r = l >> 4, c = (l & 15) * 4;
    *(float4*)&T[r][c] = *(const float4*)&W[(size_t)(k0 + r) * TDIM + n0 + c];
  }
  __syncthreads();
  const int n = tid >> 2, q = (tid & 3) * 16;
  alignas(16) unsigned short hi16[16];
  alignas(16) unsigned short lo16[16];
#pragma unroll
  for (int j = 0; j < 16; ++j) {
    const float v = T[q + j][n];
    const unsigned short h = f2bf(v);
    hi16[j] = h; lo16[j] = f2bf(v - bf2f(h));
  }
  unsigned short* dst = &Wt[(size_t)(n0 + n) * 2048];
  *(uint4*)&dst[k0 + q]          = *(uint4*)&hi16[0];
  *(uint4*)&dst[k0 + q + 8]      = *(uint4*)&hi16[8];
  *(uint4*)&dst[1024 + k0 + q]     = *(uint4*)&lo16[0];
  *(uint4*)&dst[1024 + k0 + q + 8] = *(uint4*)&lo16[8];
}

// ---------------------------------------------------------------------------
// gemm5: two-phase split-bf16 MFMA (unchanged)
// ---------------------------------------------------------------------------
__global__ __launch_bounds__(256) void gemm5(const unsigned short* __restrict__ Xs,
                                             const unsigned short* __restrict__ Wt,
                                             const float* __restrict__ bias,
                                             float* __restrict__ C,
                                             float* __restrict__ sumsq) {
  __shared__ ushort_t As[128 * 64];
  __shared__ ushort_t B0[128 * 64];
  __shared__ ushort_t B1[128 * 64];
  const int tid = threadIdx.x;
  const int wv = tid >> 6, ln = tid & 63;
  const int l16 = ln & 15, quad = ln >> 4;
  const int wrow = wv >> 1, wcol = wv & 1;
  const int row0 = blockIdx.y * 128, col0 = blockIdx.x * 128;
  const int srow = ln >> 3;
  const int sgrp = (ln & 7) ^ srow;
  f32x4 acc[4][4];
#pragma unroll
  for (int i = 0; i < 4; ++i)
#pragma unroll
    for (int j = 0; j < 4; ++j) acc[i][j] = {0.f, 0.f, 0.f, 0.f};

  for (int k0 = 0; k0 < 1024; k0 += 64) {
    __syncthreads();
#pragma unroll
    for (int i = 0; i < 4; ++i) {
      const int ci = wv * 4 + i;
      const int r = ci * 8 + srow;
      gl_lds16(&Xs[(size_t)(row0 + r) * 2048 + k0 + sgrp * 8],
               (char*)As + ci * 1024);
      gl_lds16(&Wt[(size_t)(col0 + r) * 2048 + k0 + sgrp * 8],
               (char*)B0 + ci * 1024);
      gl_lds16(&Wt[(size_t)(col0 + r) * 2048 + 1024 + k0 + sgrp * 8],
               (char*)B1 + ci * 1024);
    }
    __syncthreads();
#pragma unroll
    for (int kk = 0; kk < 2; ++kk) {
      const int slot = (kk * 4 + quad) ^ (l16 & 7);
      short8 af[4], b[4];
#pragma unroll
      for (int mi = 0; mi < 4; ++mi)
        af[mi] = *(const short8*)&As[(wrow * 64 + mi * 16 + l16) * 64 + slot * 8];
#pragma unroll
      for (int ni = 0; ni < 4; ++ni)
        b[ni] = *(const short8*)&B0[(wcol * 64 + ni * 16 + l16) * 64 + slot * 8];
#pragma unroll
      for (int mi = 0; mi < 4; ++mi)
#pragma unroll
        for (int ni = 0; ni < 4; ++ni)
          acc[mi][ni] = __builtin_amdgcn_mfma_f32_16x16x32_bf16(af[mi], b[ni], acc[mi][ni], 0, 0, 0);
#pragma unroll
      for (int ni = 0; ni < 4; ++ni)
        b[ni] = *(const short8*)&B1[(wcol * 64 + ni * 16 + l16) * 64 + slot * 8];
#pragma unroll
      for (int mi = 0; mi < 4; ++mi)
#pragma unroll
        for (int ni = 0; ni < 4; ++ni)
          acc[mi][ni] = __builtin_amdgcn_mfma_f32_16x16x32_bf16(af[mi], b[ni], acc[mi][ni], 0, 0, 0);
    }
  }
  for (int k0 = 0; k0 < 1024; k0 += 64) {
    __syncthreads();
#pragma unroll
    for (int i = 0; i < 4; ++i) {
      const int ci = wv * 4 + i;
      const int r = ci * 8 + srow;
      gl_lds16(&Xs[(size_t)(row0 + r) * 2048 + 1024 + k0 + sgrp * 8],
               (char*)As + ci * 1024);
      gl_lds16(&Wt[(size_t)(col0 + r) * 2048 + k0 + sgrp * 8],
               (char*)B0 + ci * 1024);
    }
    __syncthreads();
#pragma unroll
    for (int kk = 0; kk < 2; ++kk) {
      const int slot = (kk * 4 + quad) ^ (l16 & 7);
      short8 af[4], b[4];
#pragma unroll
      for (int mi = 0; mi < 4; ++mi)
        af[mi] = *(const short8*)&As[(wrow * 64 + mi * 16 + l16) * 64 + slot * 8];
#pragma unroll
      for (int ni = 0; ni < 4; ++ni)
        b[ni] = *(const short8*)&B0[(wcol * 64 + ni * 16 + l16) * 64 + slot * 8];
#pragma unroll
      for (int mi = 0; mi < 4; ++mi)
#pragma unroll
        for (int ni = 0; ni < 4; ++ni)
          acc[mi][ni] = __builtin_amdgcn_mfma_f32_16x16x32_bf16(af[mi], b[ni], acc[mi][ni], 0, 0, 0);
    }
  }
  float ps[4][4];
#pragma unroll
  for (int mi = 0; mi < 4; ++mi)
#pragma unroll
    for (int r = 0; r < 4; ++r) ps[mi][r] = 0.f;
#pragma unroll
  for (int ni = 0; ni < 4; ++ni) {
    const int col = col0 + wcol * 64 + ni * 16 + l16;
    const float bb = bias[col];
#pragma unroll
    for (int mi = 0; mi < 4; ++mi) {
#pragma unroll
      for (int r = 0; r < 4; ++r) {
        const int row = row0 + wrow * 64 + mi * 16 + quad * 4 + r;
        const float o = acc[mi][ni][r] + bb;
        C[(size_t)row * TDIM + col] = o;
        ps[mi][r] = fmaf(o, o, ps[mi][r]);
      }
    }
  }
#pragma unroll
  for (int mi = 0; mi < 4; ++mi) {
#pragma unroll
    for (int r = 0; r < 4; ++r) {
      float v = ps[mi][r];
      v += __shfl_xor(v, 1, 64);
      v += __shfl_xor(v, 2, 64);
      v += __shfl_xor(v, 4, 64);
      v += __shfl_xor(v, 8, 64);
      if (l16 == 0)
        atomicAdd(&sumsq[row0 + wrow * 64 + mi * 16 + quad * 4 + r], v);
    }
  }
}

// ---------------------------------------------------------------------------
// prep_wave: barrier-free per-wave prep. One wave = 8 (b,h,n) positions =
// 16 MLP rows (8 q + 8 k) = one 16x16 MFMA A-tile. NO __syncthreads:
// per-wave LDS scratch (same-wave ds ordering via lgkmcnt). F stays in
// C-layout registers; transport reductions = in-reg ct sum + 4-shfl over l16;
// q<->k pairing via shfl_xor(32) (q rows in quads 0-1, k rows in quads 2-3).
// T/Z stored bf16-hi only (R8: H-lo drop left absmax unchanged).
// Scratch/wave: T[16][72] + max(H[16][136], Z[2][16][72]) = 6912 B.
// ---------------------------------------------------------------------------
__global__ __launch_bounds__(256, 4) void prep_wave(
    const float* __restrict__ qkv, const float* __restrict__ sumsq,
    const ushort_t* __restrict__ W1s, const float* __restrict__ bp1,
    const ushort_t* __restrict__ W2s, const float* __restrict__ bp2,
    const ushort_t* __restrict__ Ms,
    ushort_t* __restrict__ Qc, ushort_t* __restrict__ Kc,
    ushort_t* __restrict__ Vt) {
  __shared__ __align__(16) char smem[4 * 6912];
  const int tid = threadIdx.x;
  const int wv = tid >> 6, ln = tid & 63;
  const int l16 = ln & 15, quad = ln >> 4;
  char* wscr = smem + wv * 6912;
  ushort_t (*T)[72]   = (ushort_t(*)[72])(wscr);           // 2304 B
  ushort_t (*Hs)[136] = (ushort_t(*)[136])(wscr + 2304);   // 4352 B
  ushort_t (*Vs)[72]  = (ushort_t(*)[72])(wscr + 2304);    // alias H (pre-L1)
  ushort_t (*Z)[16][72] = (ushort_t(*)[16][72])(wscr + 2304); // alias H (post-L2-hoist)

  const int gw = blockIdx.x * 4 + wv;
  const int p0 = gw * 8;
  const int bh = p0 >> 11, n0 = p0 & 2047;
  const int b = bh >> 4, h = bh & 15;

  // ---- stage A: T A-frags (regs) + T scratch + row norms + V out
  short8 aTh[2], aTl[2];
  float invt_l;   // inv row norm for MLP row l16 (held by all quads)
  {
    const int tp = l16 & 7, tisk = l16 >> 3;
    const size_t tb = ((size_t)(b * N_ + n0 + tp)) * TDIM + h * HD_ +
                      tisk * 1024 + quad * 8;
    const float inv = inv_norm(sumsq[b * N_ + n0 + tp]);
    float tvv[16];
    float4 t0 = *(const float4*)&qkv[tb];
    float4 t1 = *(const float4*)&qkv[tb + 4];
    float4 t2 = *(const float4*)&qkv[tb + 32];
    float4 t3 = *(const float4*)&qkv[tb + 36];
    tvv[0]=t0.x*inv; tvv[1]=t0.y*inv; tvv[2]=t0.z*inv; tvv[3]=t0.w*inv;
    tvv[4]=t1.x*inv; tvv[5]=t1.y*inv; tvv[6]=t1.z*inv; tvv[7]=t1.w*inv;
    tvv[8]=t2.x*inv; tvv[9]=t2.y*inv; tvv[10]=t2.z*inv; tvv[11]=t2.w*inv;
    tvv[12]=t3.x*inv; tvv[13]=t3.y*inv; tvv[14]=t3.z*inv; tvv[15]=t3.w*inv;
    float s = 0.f;
#pragma unroll
    for (int j = 0; j < 16; ++j) s = fmaf(tvv[j], tvv[j], s);
    s += __shfl_xor(s, 16, 64);
    s += __shfl_xor(s, 32, 64);
    invt_l = inv_norm(s);
    alignas(16) ushort_t hh[16];
    alignas(16) ushort_t llo[16];
#pragma unroll
    for (int j = 0; j < 16; ++j) {
      hh[j] = f2bf(tvv[j]);
      llo[j] = f2bf(tvv[j] - bf2f(hh[j]));
    }
    aTh[0] = *(const short8*)&hh[0]; aTh[1] = *(const short8*)&hh[8];
    aTl[0] = *(const short8*)&llo[0]; aTl[1] = *(const short8*)&llo[8];
    *(uint4*)&T[l16][quad * 8]      = *(const uint4*)&hh[0];
    *(uint4*)&T[l16][32 + quad * 8] = *(const uint4*)&hh[8];
  }
  // ---- V: |t|/||t||, transpose via scratch, one 16B store per lane
  {
    const int vp = ln >> 3, vc = (ln & 7) * 8;
    const size_t vb = ((size_t)(b * N_ + n0 + vp)) * TDIM + h * HD_ + 2048 + vc;
    float vv[8];
    float4 v0 = *(const float4*)&qkv[vb];
    float4 v1 = *(const float4*)&qkv[vb + 4];
    vv[0]=v0.x; vv[1]=v0.y; vv[2]=v0.z; vv[3]=v0.w;
    vv[4]=v1.x; vv[5]=v1.y; vv[6]=v1.z; vv[7]=v1.w;
    float sv = 0.f;
#pragma unroll
    for (int j = 0; j < 8; ++j) sv = fmaf(vv[j], vv[j], sv);
    sv += __shfl_xor(sv, 1, 64);
    sv += __shfl_xor(sv, 2, 64);
    sv += __shfl_xor(sv, 4, 64);
    const float vinv = inv_norm(sv);
    alignas(16) ushort_t vb16[8];
#pragma unroll
    for (int j = 0; j < 8; ++j) vb16[j] = f2bf(fabsf(vv[j]) * vinv);
    *(uint4*)&Vs[vp][vc] = *(const uint4*)&vb16[0];
    alignas(16) ushort_t ov[8];
#pragma unroll
    for (int p = 0; p < 8; ++p) ov[p] = Vs[p][ln];
    *(uint4*)&Vt[((size_t)(bh * 64) + ln) * N_ + n0] = *(const uint4*)&ov[0];
  }
  // invt by output row (quad*4+r)
  float invt_r[4];
#pragma unroll
  for (int r = 0; r < 4; ++r) invt_r[r] = __shfl(invt_l, quad * 4 + r, 64);

  // ---- L1: H = tanh(T @ Wp1 + b1)  [16 x 128]  (48 MFMA)
#pragma unroll
  for (int ct = 0; ct < 8; ++ct) {
    const int colg = ct * 16 + l16;
    f32x4 c = {0.f, 0.f, 0.f, 0.f};
#pragma unroll
    for (int s = 0; s < 2; ++s) {
      short8 wh = *(const short8*)&W1s[(size_t)colg * 64 + s * 32 + quad * 8];
      short8 wl = *(const short8*)&W1s[8192 + (size_t)colg * 64 + s * 32 + quad * 8];
      c = __builtin_amdgcn_mfma_f32_16x16x32_bf16(aTh[s], wh, c, 0, 0, 0);
      c = __builtin_amdgcn_mfma_f32_16x16x32_bf16(aTh[s], wl, c, 0, 0, 0);
      c = __builtin_amdgcn_mfma_f32_16x16x32_bf16(aTl[s], wh, c, 0, 0, 0);
    }
    const float bb = bp1[colg];
#pragma unroll
    for (int r = 0; r < 4; ++r)
      Hs[quad * 4 + r][colg] = f2bf(fast_tanh(c[r] + bb));
  }

  // ---- L2 + z: phase = tanh(H@Wp2 + b2)*pi; z = amp*e^{i phase}  (32 MFMA)
  {
    short8 aH[4];
#pragma unroll
    for (int s = 0; s < 4; ++s)
      aH[s] = *(const short8*)&Hs[l16][s * 32 + quad * 8];
#pragma unroll
    for (int ct = 0; ct < 4; ++ct) {
      const int d = ct * 16 + l16;
      f32x4 c = {0.f, 0.f, 0.f, 0.f};
#pragma unroll
      for (int s = 0; s < 4; ++s) {
        short8 wh = *(const short8*)&W2s[(size_t)d * 128 + s * 32 + quad * 8];
        short8 wl = *(const short8*)&W2s[8192 + (size_t)d * 128 + s * 32 + quad * 8];
        c = __builtin_amdgcn_mfma_f32_16x16x32_bf16(aH[s], wh, c, 0, 0, 0);
        c = __builtin_amdgcn_mfma_f32_16x16x32_bf16(aH[s], wl, c, 0, 0, 0);
      }
      const float b2v = bp2[d];
#pragma unroll
      for (int r = 0; r < 4; ++r) {
        const int row = quad * 4 + r;
        const float ph = fast_tanh(c[r] + b2v) * PI_F;
        const float amp = bf2f(T[row][d]) * invt_r[r];
        float sp, cp;
        __sincosf(ph, &sp, &cp);
        Z[0][row][d] = f2bf(amp * cp);   // overwrites dead H region
        Z[1][row][d] = f2bf(amp * sp);
      }
    }
  }

  // ---- flow: F = Z @ M, kept in C-layout registers  (32 MFMA)
  f32x4 cc[2][4];
  {
    short8 aZ[2][2];
#pragma unroll
    for (int comp = 0; comp < 2; ++comp)
#pragma unroll
      for (int s = 0; s < 2; ++s)
        aZ[comp][s] = *(const short8*)&Z[comp][l16][s * 32 + quad * 8];
#pragma unroll
    for (int ct = 0; ct < 4; ++ct) {
      const int colg = ct * 16 + l16;
      short8 mh[2], ml[2];
#pragma unroll
      for (int s = 0; s < 2; ++s) {
        mh[s] = *(const short8*)&Ms[(size_t)colg * 64 + s * 32 + quad * 8];
        ml[s] = *(const short8*)&Ms[4096 + (size_t)colg * 64 + s * 32 + quad * 8];
      }
#pragma unroll
      for (int comp = 0; comp < 2; ++comp) {
        f32x4 c = {0.f, 0.f, 0.f, 0.f};
#pragma unroll
        for (int s = 0; s < 2; ++s) {
          c = __builtin_amdgcn_mfma_f32_16x16x32_bf16(aZ[comp][s], mh[s], c, 0, 0, 0);
          c = __builtin_amdgcn_mfma_f32_16x16x32_bf16(aZ[comp][s], ml[s], c, 0, 0, 0);
        }
        cc[comp][ct] = c;
      }
    }
  }

  // ---- normalize + transport, natively in C-layout.
  // rows quad*4+r: quads 0,1 = q rows (positions (quad&1)*4+r),
  //               quads 2,3 = k rows (same positions).
  const bool isk = quad >= 2;
#pragma unroll
  for (int r = 0; r < 4; ++r) {
    float fr[4], fi[4];
#pragma unroll
    for (int ct = 0; ct < 4; ++ct) { fr[ct] = cc[0][ct][r]; fi[ct] = cc[1][ct][r]; }
    // self row norm (reduce over ct in-reg, l16 via 4 shfls)
    float s = 0.f;
#pragma unroll
    for (int ct = 0; ct < 4; ++ct) s += fmaf(fr[ct], fr[ct], fi[ct] * fi[ct]);
    s += __shfl_xor(s, 1, 64); s += __shfl_xor(s, 2, 64);
    s += __shfl_xor(s, 4, 64); s += __shfl_xor(s, 8, 64);
    const float invn_ = inv_norm(s);
#pragma unroll
    for (int ct = 0; ct < 4; ++ct) { fr[ct] *= invn_; fi[ct] *= invn_; }
    // exchange with partner row (q<->k), already normalized
    float or_[4], oi_[4];
#pragma unroll
    for (int ct = 0; ct < 4; ++ct) {
      or_[ct] = __shfl_xor(fr[ct], 32, 64);
      oi_[ct] = __shfl_xor(fi[ct], 32, 64);
    }
    float qr[4], qi[4], kr[4], ki[4];
#pragma unroll
    for (int ct = 0; ct < 4; ++ct) {
      qr[ct] = isk ? or_[ct] : fr[ct];
      qi[ct] = isk ? oi_[ct] : fi[ct];
      kr[ct] = isk ? fr[ct] : or_[ct];
      ki[ct] = isk ? fi[ct] : oi_[ct];
    }
    // transport: dist = csqrt(sum(diff^2)), tf = 1/(1+cexp(10*dist))
    float sA = 0.f, sB = 0.f;
    float dr[4], di[4];
#pragma unroll
    for (int ct = 0; ct < 4; ++ct) {
      dr[ct] = kr[ct] - qr[ct];
      di[ct] = ki[ct] - qi[ct];
      sA += fmaf(dr[ct], dr[ct], -di[ct] * di[ct]);
      sB += 2.0f * dr[ct] * di[ct];
    }
    sA += __shfl_xor(sA, 1, 64); sA += __shfl_xor(sA, 2, 64);
    sA += __shfl_xor(sA, 4, 64); sA += __shfl_xor(sA, 8, 64);
    sB += __shfl_xor(sB, 1, 64); sB += __shfl_xor(sB, 2, 64);
    sB += __shfl_xor(sB, 4, 64); sB += __shfl_xor(sB, 8, 64);
    const float rad = sqrtf(fmaf(sA, sA, sB * sB));
    const float ur = sqrtf(fmaxf((rad + sA) * 0.5f, 0.0f));
    const float ui = copysignf(sqrtf(fmaxf((rad - sA) * 0.5f, 0.0f)), sB);
    const float er = __expf(10.0f * ur);
    float s10, c10;
    __sincosf(10.0f * ui, &s10, &c10);
    const float exr = er * c10, exi = er * s10;
    const float dnr = 1.0f + exr, dni = exi;
    const float rd2 = __builtin_amdgcn_rcpf(fmaf(dnr, dnr, dni * dni));
    const float tfr = dnr * rd2, tfi = -dni * rd2;
    const float omr = 1.0f - tfr, omi = -tfi;
    float ktr[4], kti[4];
    float s2 = 0.f;
#pragma unroll
    for (int ct = 0; ct < 4; ++ct) {
      ktr[ct] = kr[ct] * tfr - ki[ct] * tfi + qr[ct] * omr - qi[ct] * omi;
      kti[ct] = kr[ct] * tfi + ki[ct] * tfr + qr[ct] * omi + qi[ct] * omr;
      s2 += fmaf(ktr[ct], ktr[ct], kti[ct] * kti[ct]);
    }
    s2 += __shfl_xor(s2, 1, 64); s2 += __shfl_xor(s2, 2, 64);
    s2 += __shfl_xor(s2, 4, 64); s2 += __shfl_xor(s2, 8, 64);
    const float inv2 = inv_norm(s2);
    // stores: quads 0,1 write Qc; quads 2,3 write Kc (positions (quad&1)*4+r)
    const int p = (quad & 1) * 4 + r;
    const size_t o = ((size_t)bh * N_ + n0 + p) * 128;
    if (!isk) {
#pragma unroll
      for (int ct = 0; ct < 4; ++ct) {
        const int d = ct * 16 + l16;
        Qc[o + d]      = f2bf(qr[ct]);
        Qc[o + 64 + d] = f2bf(qi[ct]);
      }
    } else {
#pragma unroll
      for (int ct = 0; ct < 4; ++ct) {
        const int d = ct * 16 + l16;
        Kc[o + d]      = f2bf(ktr[ct] * inv2);
        Kc[o + 64 + d] = f2bf(-kti[ct] * inv2);   // negated: S = qr.kr + qi.(-ki)
      }
    }
  }
}

// ---------------------------------------------------------------------------
// attn3: 32x32x16 MFMA flash -- unchanged
// ---------------------------------------------------------------------------
__global__ __launch_bounds__(256, 2) void attn3(
    const ushort_t* __restrict__ Qc, const ushort_t* __restrict__ Kc,
    const ushort_t* __restrict__ Vt, float* __restrict__ out) {
  __shared__ __align__(16) char smem[35328];
  ushort_t* Ks = (ushort_t*)smem;
  ushort_t* Vs = (ushort_t*)(smem + 16384);
  float (*Of)[68] = (float(*)[68])smem;
  float* Dd = (float*)(smem + 34816);

  const int tid = threadIdx.x;
  const int wv = tid >> 6, ln = tid & 63;
  const int l31 = ln & 31, hi = ln >> 5;
  const int qh = wv & 1, kh = wv >> 1;
  const int bh = blockIdx.y;
  const int q0 = blockIdx.x * 128;
  const size_t hb = (size_t)bh * N_;

  short8 qf[2][8];
#pragma unroll
  for (int nt = 0; nt < 2; ++nt) {
    const size_t qrow = (hb + q0 + qh * 64 + nt * 32 + l31) * 128;
#pragma unroll
    for (int s = 0; s < 8; ++s)
      qf[nt][s] = *(const short8*)&Qc[qrow + s * 16 + hi * 8];
  }

  f32x16 oacc[2][2];
#pragma unroll
  for (int i = 0; i < 2; ++i)
#pragma unroll
    for (int j = 0; j < 2; ++j)
#pragma unroll
      for (int r = 0; r < 16; ++r) oacc[i][j][r] = 0.f;
  float den[2] = {0.f, 0.f};

  const int rK = kh * 32 + l31;
  for (int kt = 0; kt < N_ / 64; ++kt) {
    const size_t kbase = (hb + kt * 64) * 128;
    __syncthreads();
#pragma unroll
    for (int i = 0; i < 4; ++i) {
      const int l = tid + i * 256;
      const int r = l >> 4, c = l & 15;
      uint4 v = *(const uint4*)&Kc[kbase + (size_t)r * 128 + c * 8];
      *(uint4*)&Ks[r * 128 + ((c ^ (r & 15)) * 8)] = v;
    }
#pragma unroll
    for (int i = 0; i < 2; ++i) {
      const int l = tid + i * 256;
      const int r = l >> 3, c = l & 7;
      uint4 v = *(const uint4*)&Vt[((size_t)bh * 64 + r) * N_ + kt * 64 + c * 8];
      *(uint4*)&Vs[r * 128 + ((c ^ (r & 15)) * 8)] = v;
    }
    __syncthreads();

    f32x16 sacc[2];
#pragma unroll
    for (int nt = 0; nt < 2; ++nt)
#pragma unroll
      for (int r = 0; r < 16; ++r) sacc[nt][r] = 0.f;
#pragma unroll
    for (int s = 0; s < 8; ++s) {
      const int c = s * 2 + hi;
      short8 ak = *(const short8*)&Ks[rK * 128 + ((c ^ (rK & 15)) * 8)];
      sacc[0] = __builtin_amdgcn_mfma_f32_32x32x16_bf16(ak, qf[0][s], sacc[0], 0, 0, 0);
      sacc[1] = __builtin_amdgcn_mfma_f32_32x32x16_bf16(ak, qf[1][s], sacc[1], 0, 0, 0);
    }

    short8 pfrag[2][2];
#pragma unroll
    for (int nt = 0; nt < 2; ++nt) {
      float pv[16];
      float dl = 0.f;
#pragma unroll
      for (int r = 0; r < 16; ++r) {
        pv[r] = __expf(sacc[nt][r] * SCALE_F);
        dl += pv[r];
      }
      den[nt] += dl;
      unsigned u8a[8], pu[8];
#pragma unroll
      for (int t = 0; t < 8; ++t)
        u8a[t] = (unsigned)f2bf(pv[2 * t]) | ((unsigned)f2bf(pv[2 * t + 1]) << 16);
#pragma unroll
      for (int t = 0; t < 8; ++t)
        pu[t] = (unsigned)__shfl_xor((int)u8a[t], 32, 64);
#pragma unroll
      for (int s2 = 0; s2 < 2; ++s2) {
        u32x4 fu;
        if (hi == 0) {
          fu[0] = u8a[4 * s2]; fu[1] = u8a[4 * s2 + 1];
          fu[2] = pu[4 * s2];  fu[3] = pu[4 * s2 + 1];
        } else {
          fu[0] = pu[4 * s2 + 2];  fu[1] = pu[4 * s2 + 3];
          fu[2] = u8a[4 * s2 + 2]; fu[3] = u8a[4 * s2 + 3];
        }
        pfrag[nt][s2] = __builtin_bit_cast(short8, fu);
      }
    }

#pragma unroll
    for (int s2 = 0; s2 < 2; ++s2) {
#pragma unroll
      for (int dt = 0; dt < 2; ++dt) {
        const int rV = dt * 32 + l31;
        const int c = kh * 4 + s2 * 2 + hi;
        short8 bv = *(const short8*)&Vs[rV * 128 + ((c ^ (rV & 15)) * 8)];
        oacc[0][dt] = __builtin_amdgcn_mfma_f32_32x32x16_bf16(pfrag[0][s2], bv, oacc[0][dt], 0, 0, 0);
        oacc[1][dt] = __builtin_amdgcn_mfma_f32_32x32x16_bf16(pfrag[1][s2], bv, oacc[1][dt], 0, 0, 0);
      }
    }
  }

#pragma unroll
  for (int nt = 0; nt < 2; ++nt)
    den[nt] += __shfl_xor(den[nt], 32, 64);

  __syncthreads();
  if (kh == 0) {
#pragma unroll
    for (int nt = 0; nt < 2; ++nt) {
#pragma unroll
      for (int dt = 0; dt < 2; ++dt)
#pragma unroll
        for (int r = 0; r < 16; ++r) {
          const int row = qh * 64 + nt * 32 + (r & 3) + 8 * (r >> 2) + 4 * hi;
          Of[row][dt * 32 + l31] = oacc[nt][dt][r];
        }
      if (hi == 0) Dd[qh * 64 + nt * 32 + l31] = den[nt];
    }
  }
  __syncthreads();
  if (kh == 1) {
#pragma unroll
    for (int nt = 0; nt < 2; ++nt) {
#pragma unroll
      for (int dt = 0; dt < 2; ++dt)
#pragma unroll
        for (int r = 0; r < 16; ++r) {
          const int row = qh * 64 + nt * 32 + (r & 3) + 8 * (r >> 2) + 4 * hi;
          Of[row][dt * 32 + l31] += oacc[nt][dt][r];
        }
      if (hi == 0) Dd[qh * 64 + nt * 32 + l31] += den[nt];
    }
  }
  __syncthreads();

  {
    const int ql = tid >> 1, half = tid & 1;
    const int b = bh >> 4, h = bh & 15;
    const float invd = __builtin_amdgcn_rcpf(Dd[ql]);
    float* op = &out[(((size_t)b * N_ + q0 + ql) * H_ + h) * HD_ + half * 32];
#pragma unroll
    for (int j = 0; j < 8; ++j) {
      float4 o = *(const float4*)&Of[ql][half * 32 + j * 4];
      o.x *= invd; o.y *= invd; o.z *= invd; o.w *= invd;
      *(float4*)&op[j * 4] = o;
    }
  }
}

// ---------------------------------------------------------------------------
extern "C" void kernel_launch(void* const* d_in, const int* in_sizes, int n_in,
                              void* d_out, int out_size, void* d_ws, size_t ws_size,
                              hipStream_t stream) {
  const float* x    = (const float*)d_in[0];
  const float* Wqkv = (const float*)d_in[1];
  const float* bqkv = (const float*)d_in[2];
  const float* Wp1  = (const float*)d_in[3];
  const float* bp1  = (const float*)d_in[4];
  const float* Wp2  = (const float*)d_in[5];
  const float* bp2  = (const float*)d_in[6];
  const float* Wf   = (const float*)d_in[7];
  float* out = (float*)d_out;

  char* w = (char*)d_ws;
  float* qkv = (float*)w;               w += (size_t)ROWS * TDIM * 4;
  float* sumsq = (float*)w;             w += (size_t)ROWS * 4;
  ushort_t* Ms  = (ushort_t*)w;         w += 2 * 4096 * 2;
  ushort_t* W1s = (ushort_t*)w;         w += 2 * 8192 * 2;
  ushort_t* W2s = (ushort_t*)w;         w += 2 * 8192 * 2;
  unsigned short* Xs = (unsigned short*)w; w += (size_t)ROWS * 2048 * 2;
  unsigned short* Wt = (unsigned short*)w; w += (size_t)TDIM * 2048 * 2;
  unsigned short* Qc = (unsigned short*)w; w += (size_t)32 * N_ * 128 * 2;
  unsigned short* Kc = (unsigned short*)w; w += (size_t)32 * N_ * 128 * 2;
  unsigned short* Vt = (unsigned short*)w; w += (size_t)32 * 64 * N_ * 2;

  hipLaunchKernelGGL(split_X, dim3(ROWS * 1024 / 4 / 256), dim3(256), 0, stream, x, Xs);
  hipLaunchKernelGGL(split_W, dim3(48, 16), dim3(256), 0, stream, Wqkv, Wt);
  hipLaunchKernelGGL(compute_M, dim3(1), dim3(256), 0, stream, Wf, Ms);
  hipLaunchKernelGGL(prep_w, dim3(1), dim3(256), 0, stream, Wp1, Wp2, W1s, W2s);
  hipLaunchKernelGGL(zero_sumsq, dim3(1), dim3(256), 0, stream, sumsq);
  hipLaunchKernelGGL(gemm5, dim3(24, 32), dim3(256), 0, stream, Xs, Wt, bqkv, qkv, sumsq);
  hipLaunchKernelGGL(prep_wave, dim3(2048), dim3(256), 0, stream,
                     qkv, sumsq, W1s, bp1, W2s, bp2, Ms, Qc, Kc, Vt);
  hipLaunchKernelGGL(attn3, dim3(N_ / 128, B_ * H_), dim3(256), 0, stream,
                     Qc, Kc, Vt, out);
}